// Round 1
// baseline (1213.127 us; speedup 1.0000x reference)
//
#include <hip/hip_runtime.h>
#include <math.h>

#define FRAME 128
#define HOPW 64
#define SLEN 65536
#define IRLEN 1024
#define NFB 1006          // (65536 - 1151 - 1) / 64
#define RMASK 2047
#define PI_D 3.14159265358979323846

__device__ __forceinline__ float clip1(float v) { return fminf(1.0f, fmaxf(-1.0f, v)); }

// ---------------- Kernel 1: IR scaling (get_MSG + scale_IR) ----------------
__global__ __launch_bounds__(1024) void scale_ir_kernel(const float* __restrict__ ir,
                                                        float* __restrict__ irs) {
    __shared__ float xl[IRLEN];
    __shared__ float rmax[1024];
    __shared__ float rsum[1024];
    __shared__ float fbc;
    int tid = threadIdx.x;
    xl[tid] = ir[tid];
    __syncthreads();

    float pw = 0.f;
    int ok = 0;
    if (tid < 513) {
        // direct DFT bin via double-precision rotation recurrence
        double th = -2.0 * PI_D * (double)tid / 1024.0;
        double cr = cos(th), ci = sin(th);
        double wr = 1.0, wi = 0.0, re = 0.0, im = 0.0;
        for (int n = 0; n < IRLEN; ++n) {
            double xv = (double)xl[n];
            re += xv * wr;
            im += xv * wi;
            double nr = wr * cr - wi * ci;
            wi = wr * ci + wi * cr;
            wr = nr;
        }
        float mag = (float)sqrt(re * re + im * im);   // |spec| then square, like reference
        pw = mag * mag;
        double ph = atan2(im, re);
        ok = (ph > -0.1 && ph < 0.1) ? 1 : 0;
    }
    rmax[tid] = (tid < 513 && ok) ? pw : -INFINITY;
    rsum[tid] = (tid < 513) ? pw : 0.f;
    __syncthreads();
    for (int s = 512; s > 0; s >>= 1) {
        if (tid < s) {
            rmax[tid] = fmaxf(rmax[tid], rmax[tid + s]);
            rsum[tid] = rsum[tid] + rsum[tid + s];
        }
        __syncthreads();
    }
    if (tid == 0) {
        float peak = rmax[0];
        float MLG = rsum[0] / 513.0f;
        float MSG = -10.0f * log10f(peak / MLG);
        float target_gain = MSG + 2.0f;
        float mean_gain = 10.0f * log10f(MLG);
        fbc = powf(0.5f, (target_gain - mean_gain) / 6.0f);
    }
    __syncthreads();
    irs[tid] = ir[tid] / fbc;
}

// ---------------- Kernel 2: sequential howling loop ----------------
// 768 threads = 12 waves. Thread layout: kg = tid/192 (k-group of 32 taps,
// wave-uniform since 192 = 3 waves), ob = tid%192 (block of 6 conv outputs).
// Each thread keeps its constant 37-float IR window in registers.
__global__ __launch_bounds__(768) void howl_kernel(const float* __restrict__ x,
                                                   const float* __restrict__ irs,
                                                   float* __restrict__ out) {
    __shared__ float ring[2048];      // circular window of x: [i*64, i*64+1216)
    __shared__ float wlds[FRAME];     // current windowed frame w_i
    __shared__ float winv[FRAME];     // hann window
    __shared__ float tail[HOPW];      // w_{i-1}[64:128] for overlap-add
    __shared__ float part[4 * 1152];  // per-k-group partial conv outputs

    int tid = threadIdx.x;
    int lane = tid & 63;
    int kg = tid / 192;
    int ob = tid % 192;
    int q = ob * 6;               // first conv output owned by this thread
    int lo = q - kg * 32 - 31;    // base of constant IR register window

    float wir[37];
#pragma unroll
    for (int j = 0; j < 37; ++j) {
        int idx = lo + j;
        wir[j] = (idx >= 0 && idx < IRLEN) ? irs[idx] : 0.f;
    }

    if (tid < FRAME) winv[tid] = (float)(0.5 * (1.0 - cos(PI_D * (double)tid / 64.0)));
    if (tid < HOPW) tail[tid] = 0.f;
    for (int idx = tid; idx < 1216; idx += 768) ring[idx] = x[idx];  // raw (frame 0 reads raw)
    __syncthreads();
    if (tid < FRAME) wlds[tid] = winv[tid] * ring[tid];  // w_0
    __syncthreads();

#pragma unroll 1
    for (int i = 0; i < NFB; ++i) {
        int base = i * HOPW;

        // --- Phase B: prefetch incoming x, conv partials (FMA), OLA store ---
        float xv = 0.f;
        if (tid >= 64 && tid < 128) {
            int g = base + 1216 + (tid - 64);
            if (g < SLEN) xv = x[g];
        }
        float wreg = wlds[kg * 32 + (lane & 31)];  // lane j holds w[kg*32+j] (j<32)
        float a0 = 0, a1 = 0, a2 = 0, a3 = 0, a4 = 0, a5 = 0;
#pragma unroll
        for (int kk = 0; kk < 32; ++kk) {
            // k = kg*32 + 31 - kk ; wave-uniform scalar via readlane -> SGPR FMA operand
            float s = __int_as_float(__builtin_amdgcn_readlane(__float_as_int(wreg), 31 - kk));
            a0 = fmaf(s, wir[kk + 0], a0);
            a1 = fmaf(s, wir[kk + 1], a1);
            a2 = fmaf(s, wir[kk + 2], a2);
            a3 = fmaf(s, wir[kk + 3], a3);
            a4 = fmaf(s, wir[kk + 4], a4);
            a5 = fmaf(s, wir[kk + 5], a5);
        }
        if (tid < 64) {  // overlap-add output block i
            float w0 = wlds[tid];
            out[base + tid] = clip1(w0 + tail[tid]);
            tail[tid] = wlds[64 + tid];
        }
        float* pp = &part[kg * 1152 + q];
        pp[0] = a0; pp[1] = a1; pp[2] = a2; pp[3] = a3; pp[4] = a4; pp[5] = a5;
        __syncthreads();

        // --- Phase C: reduce partials, ring add+clip, next frame, commit prefetch ---
        for (int p = tid; p < 1152; p += 768) {
            float s = part[p] + part[1152 + p] + part[2 * 1152 + p] + part[3 * 1152 + p];
            int slot = (base + 64 + p) & RMASK;
            float v = clip1(ring[slot] + s);
            ring[slot] = v;
            if (p < FRAME) wlds[p] = winv[p] * v;  // w_{i+1}
        }
        if (tid >= 64 && tid < 128) {
            int slot = (base + 1216 + (tid - 64)) & RMASK;
            ring[slot] = clip1(xv);  // whole-array clip semantics on entry
        }
        __syncthreads();
    }

    // --- Epilogue: last frame's OLA blocks + zero tail ---
    if (tid < 64) out[64384 + tid] = clip1(wlds[tid] + tail[tid]);
    else if (tid < 128) out[64384 + tid] = clip1(wlds[tid]);
    for (int idx = 64512 + tid; idx < SLEN; idx += 768) out[idx] = 0.f;
}

extern "C" void kernel_launch(void* const* d_in, const int* in_sizes, int n_in,
                              void* d_out, int out_size, void* d_ws, size_t ws_size,
                              hipStream_t stream) {
    const float* x = (const float*)d_in[0];
    const float* ir = (const float*)d_in[1];
    float* out = (float*)d_out;
    float* irs = (float*)d_ws;  // 1024 floats of scratch: scaled IR

    hipLaunchKernelGGL(scale_ir_kernel, dim3(1), dim3(1024), 0, stream, ir, irs);
    hipLaunchKernelGGL(howl_kernel, dim3(1), dim3(768), 0, stream, x, irs, out);
}

// Round 2
// 1057.993 us; speedup vs baseline: 1.1466x; 1.1466x over previous
//
#include <hip/hip_runtime.h>
#include <math.h>

#define FRAME 128
#define HOPW 64
#define SLEN 65536
#define IRLEN 1024
#define NFB 1006          // (65536 - 1151 - 1) / 64
#define RMASK 2047
#define PI_D 3.14159265358979323846

__device__ __forceinline__ float clip1(float v) { return fminf(1.0f, fmaxf(-1.0f, v)); }

// Raw barrier: drains LDS ops only; global loads/stores stay in flight
// (counted vmcnt waits are inserted by the compiler exactly at use points).
__device__ __forceinline__ void loop_barrier() {
    __builtin_amdgcn_sched_barrier(0);
    asm volatile("s_waitcnt lgkmcnt(0)" ::: "memory");
    __builtin_amdgcn_s_barrier();
    __builtin_amdgcn_sched_barrier(0);
}

// One fused kernel: IR scaling prologue (DFT in LDS) + sequential howling loop.
// 768 threads = 12 waves. FMA layout: kg = tid/192 (32-tap group, wave-uniform),
// ob = tid%192 -> 6 conv outputs; constant 37-float IR window in VGPRs.
__global__ __launch_bounds__(768) void howl_fused(const float* __restrict__ x,
                                                  const float* __restrict__ ir,
                                                  float* __restrict__ out) {
    __shared__ float ring[2048];         // circular raw/updated x window
    __shared__ float part[2][4][1152];   // double-buffered per-kg conv partials
    __shared__ float irl[IRLEN];         // raw IR (prologue), stays resident
    __shared__ float wlds[FRAME];        // current windowed frame w_i
    __shared__ float winv[FRAME];        // hann window
    __shared__ float tailb[HOPW];        // w_{i-1}[64:128]
    __shared__ float red1[1024];
    __shared__ float red2[1024];
    __shared__ float invfs;

    const int tid = threadIdx.x;
    const int lane = tid & 63;
    const int kg = tid / 192;
    const int ob = tid % 192;
    const int q = ob * 6;
    const int lo = q - kg * 32 - 31;

    // ---- prologue: stage IR + raw x window + window table ----
    for (int idx = tid; idx < IRLEN; idx += 768) irl[idx] = ir[idx];
    for (int idx = tid; idx < 1216; idx += 768) ring[idx] = x[idx];  // raw (frame 0 reads raw)
    if (tid < FRAME) winv[tid] = (float)(0.5 * (1.0 - cos(PI_D * (double)tid / 64.0)));
    if (tid < HOPW) tailb[tid] = 0.f;
    if (tid >= 513) { red1[tid] = -INFINITY; red2[tid] = 0.f; }
    if (tid < 256) { red1[768 + tid] = -INFINITY; red2[768 + tid] = 0.f; }
    __syncthreads();

    // ---- DFT power spectrum (4-way ILP recurrence, double precision) ----
    if (tid < 513) {
        double th = -2.0 * PI_D * (double)tid / 1024.0;
        double c4 = cos(4.0 * th), s4 = sin(4.0 * th);
        double wr0 = 1.0,           wi0 = 0.0;
        double wr1 = cos(th),       wi1 = sin(th);
        double wr2 = cos(2.0 * th), wi2 = sin(2.0 * th);
        double wr3 = cos(3.0 * th), wi3 = sin(3.0 * th);
        double ar0 = 0, ai0 = 0, ar1 = 0, ai1 = 0, ar2 = 0, ai2 = 0, ar3 = 0, ai3 = 0;
        for (int m = 0; m < 256; ++m) {
            double x0 = irl[4 * m], x1 = irl[4 * m + 1], x2 = irl[4 * m + 2], x3 = irl[4 * m + 3];
            ar0 += x0 * wr0; ai0 += x0 * wi0;
            ar1 += x1 * wr1; ai1 += x1 * wi1;
            ar2 += x2 * wr2; ai2 += x2 * wi2;
            ar3 += x3 * wr3; ai3 += x3 * wi3;
            double t;
            t = wr0 * c4 - wi0 * s4; wi0 = wr0 * s4 + wi0 * c4; wr0 = t;
            t = wr1 * c4 - wi1 * s4; wi1 = wr1 * s4 + wi1 * c4; wr1 = t;
            t = wr2 * c4 - wi2 * s4; wi2 = wr2 * s4 + wi2 * c4; wr2 = t;
            t = wr3 * c4 - wi3 * s4; wi3 = wr3 * s4 + wi3 * c4; wr3 = t;
        }
        double re = (ar0 + ar1) + (ar2 + ar3);
        double im = (ai0 + ai1) + (ai2 + ai3);
        float mag = (float)sqrt(re * re + im * im);
        float pw = mag * mag;
        double ph = atan2(im, re);
        int ok = (ph > -0.1 && ph < 0.1) ? 1 : 0;
        red1[tid] = ok ? pw : -INFINITY;
        red2[tid] = pw;
    }
    __syncthreads();
    for (int s = 512; s > 0; s >>= 1) {
        if (tid < s) {
            red1[tid] = fmaxf(red1[tid], red1[tid + s]);
            red2[tid] = red2[tid] + red2[tid + s];
        }
        __syncthreads();
    }
    if (tid == 0) {
        float peak = red1[0];
        float MLG = red2[0] / 513.0f;
        float MSG = -10.0f * log10f(peak / MLG);
        float target_gain = MSG + 2.0f;
        float mean_gain = 10.0f * log10f(MLG);
        invfs = powf(0.5f, (target_gain - mean_gain) / 6.0f);
    }
    __syncthreads();

    const float fbc = invfs;
    float wir[37];
#pragma unroll
    for (int j = 0; j < 37; ++j) {
        int idx = lo + j;
        wir[j] = (idx >= 0 && idx < IRLEN) ? irl[idx] / fbc : 0.f;
    }
    float xv = 0.f;
    if (tid >= 64 && tid < 128) xv = x[1216 + (tid - 64)];  // prefetch for iter 0 commit
    if (tid < FRAME) wlds[tid] = winv[tid] * ring[tid];      // w_0 from raw x
    __syncthreads();

    int pb = 0;
#pragma unroll 1
    for (int i = 0; i < NFB; ++i) {
        const int base = i * HOPW;

        float wreg = wlds[kg * 32 + (lane & 31)];  // lane j holds w[kg*32+j]

        // wave 0: overlap-add output block i ; wave 1: x commit + prefetch
        if (tid < 64) {
            float w0 = wlds[tid];
            float w1 = wlds[64 + tid];
            out[base + tid] = clip1(w0 + tailb[tid]);
            tailb[tid] = w1;
        } else if (tid < 128) {
            int t = tid - 64;
            int pos = base + 1216 + t;
            if (pos < SLEN) ring[pos & RMASK] = clip1(xv);  // uses load from prev iter
            int npos = pos + HOPW;
            xv = (npos < SLEN) ? x[npos] : 0.f;             // prefetch next (stays in flight)
        }

        // C_tail of conv_{i-1}: outputs p in [128,1152), overlapped with FMA phase
        if (i > 0) {
            const float* pprev = &part[pb ^ 1][0][0];
            {
                int p = 128 + tid;
                int slot = (base + p) & RMASK;
                float s = pprev[p] + pprev[1152 + p] + pprev[2 * 1152 + p] + pprev[3 * 1152 + p];
                ring[slot] = clip1(ring[slot] + s);
            }
            if (tid >= 256 && tid < 512) {
                int p = 896 + (tid - 256);
                int slot = (base + p) & RMASK;
                float s = pprev[p] + pprev[1152 + p] + pprev[2 * 1152 + p] + pprev[3 * 1152 + p];
                ring[slot] = clip1(ring[slot] + s);
            }
        }

        // conv partials for frame i (w in SGPR via readlane, IR window in VGPRs)
        float a0 = 0, a1 = 0, a2 = 0, a3 = 0, a4 = 0, a5 = 0;
#pragma unroll
        for (int kk = 0; kk < 32; ++kk) {
            float s = __int_as_float(__builtin_amdgcn_readlane(__float_as_int(wreg), 31 - kk));
            a0 = fmaf(s, wir[kk + 0], a0);
            a1 = fmaf(s, wir[kk + 1], a1);
            a2 = fmaf(s, wir[kk + 2], a2);
            a3 = fmaf(s, wir[kk + 3], a3);
            a4 = fmaf(s, wir[kk + 4], a4);
            a5 = fmaf(s, wir[kk + 5], a5);
        }
        float* pp = &part[pb][kg][q];
        *(float2*)(pp + 0) = make_float2(a0, a1);
        *(float2*)(pp + 2) = make_float2(a2, a3);
        *(float2*)(pp + 4) = make_float2(a4, a5);

        loop_barrier();

        // head: conv_i outputs p in [0,128) -> ring RMW + next frame w_{i+1}
        if (tid < 128) {
            const float* pcur = &part[pb][0][0];
            int slot = (base + 64 + tid) & RMASK;
            float s = pcur[tid] + pcur[1152 + tid] + pcur[2 * 1152 + tid] + pcur[3 * 1152 + tid];
            float v = clip1(ring[slot] + s);
            ring[slot] = v;
            wlds[tid] = winv[tid] * v;
        }

        loop_barrier();
        pb ^= 1;
    }

    // ---- epilogue: last frame's OLA blocks + zero tail ----
    if (tid < 64) out[64384 + tid] = clip1(wlds[tid] + tailb[tid]);
    else if (tid < 128) out[64384 + tid] = clip1(wlds[tid]);
    for (int idx = 64512 + tid; idx < SLEN; idx += 768) out[idx] = 0.f;
}

extern "C" void kernel_launch(void* const* d_in, const int* in_sizes, int n_in,
                              void* d_out, int out_size, void* d_ws, size_t ws_size,
                              hipStream_t stream) {
    const float* x = (const float*)d_in[0];
    const float* ir = (const float*)d_in[1];
    float* out = (float*)d_out;
    (void)d_ws; (void)ws_size; (void)in_sizes; (void)n_in; (void)out_size;

    hipLaunchKernelGGL(howl_fused, dim3(1), dim3(768), 0, stream, x, ir, out);
}